// Round 1
// baseline (1196.338 us; speedup 1.0000x reference)
//
#include <hip/hip_runtime.h>

#define HID 50
#define NMID 7

__device__ __forceinline__ float tanh_fast(float v) {
    // tanh(x) = 1 - 2/(exp(2x)+1); exp(2x) = exp2(x * 2*log2(e))
    float e = __builtin_amdgcn_exp2f(v * 2.885390081777927f);
    return 1.0f - 2.0f * __builtin_amdgcn_rcpf(e + 1.0f);
}

__global__ __launch_bounds__(256, 4) void softmesh_mlp(
    const float* __restrict__ x, const float* __restrict__ y,
    const float* __restrict__ z,
    const float* __restrict__ W_in, const float* __restrict__ b_in,
    const float* __restrict__ W_mid, const float* __restrict__ b_mid,
    const float* __restrict__ W_out, const float* __restrict__ b_out,
    float* __restrict__ out, int n)
{
    int i = blockIdx.x * blockDim.x + threadIdx.x;
    if (i >= n) return;

    float in0 = x[i];
    float in1 = y[i];
    float in2 = z[i];

    float h[HID];
    float acc[HID];

    // input layer: [3] @ [3,50] + b -> tanh
#pragma unroll
    for (int j = 0; j < HID; ++j) {
        float a = b_in[j];
        a = fmaf(in0, W_in[0 * HID + j], a);
        a = fmaf(in1, W_in[1 * HID + j], a);
        a = fmaf(in2, W_in[2 * HID + j], a);
        h[j] = tanh_fast(a);
    }

    // 7 mid layers: [50] @ [50,50] + b -> tanh
    // Keep the layer loop ROLLED (body ~2500 v_fmac ≈ 11 KB, fits I-cache;
    // unrolling x7 would blow the 32 KB I-cache).
#pragma unroll 1
    for (int L = 0; L < NMID; ++L) {
        const float* __restrict__ W = W_mid + L * HID * HID;
        const float* __restrict__ b = b_mid + L * HID;
#pragma unroll
        for (int j = 0; j < HID; ++j) acc[j] = b[j];
#pragma unroll
        for (int k = 0; k < HID; ++k) {
            float hk = h[k];
            // W row k is contiguous; uniform address -> s_load, FMA src0 = SGPR
#pragma unroll
            for (int j = 0; j < HID; ++j) {
                acc[j] = fmaf(hk, W[k * HID + j], acc[j]);
            }
        }
#pragma unroll
        for (int j = 0; j < HID; ++j) h[j] = tanh_fast(acc[j]);
    }

    // output layer: [50] @ [50,3] + b
    float u0 = b_out[0];
    float u1 = b_out[1];
    float u2 = b_out[2];
#pragma unroll
    for (int k = 0; k < HID; ++k) {
        float hk = h[k];
        u0 = fmaf(hk, W_out[k * 3 + 0], u0);
        u1 = fmaf(hk, W_out[k * 3 + 1], u1);
        u2 = fmaf(hk, W_out[k * 3 + 2], u2);
    }

    // outputs are the tuple (U[:,0], U[:,1], U[:,2]) concatenated flat
    out[i]         = u0;
    out[i + n]     = u1;
    out[i + 2 * n] = u2;
}

extern "C" void kernel_launch(void* const* d_in, const int* in_sizes, int n_in,
                              void* d_out, int out_size, void* d_ws, size_t ws_size,
                              hipStream_t stream) {
    const float* x     = (const float*)d_in[0];
    const float* y     = (const float*)d_in[1];
    const float* z     = (const float*)d_in[2];
    const float* W_in  = (const float*)d_in[3];
    const float* b_in  = (const float*)d_in[4];
    const float* W_mid = (const float*)d_in[5];
    const float* b_mid = (const float*)d_in[6];
    const float* W_out = (const float*)d_in[7];
    const float* b_out = (const float*)d_in[8];
    float* out = (float*)d_out;

    int n = in_sizes[0];
    int block = 256;
    int grid = (n + block - 1) / block;
    softmesh_mlp<<<grid, block, 0, stream>>>(x, y, z, W_in, b_in, W_mid, b_mid,
                                             W_out, b_out, out, n);
}

// Round 2
// 1195.269 us; speedup vs baseline: 1.0009x; 1.0009x over previous
//
#include <hip/hip_runtime.h>

#define HID 50
#define NMID 7

__device__ __forceinline__ float tanh_fast(float v) {
    // tanh(x) = 1 - 2/(exp(2x)+1); exp(2x) = exp2(x * 2*log2(e))
    float e = __builtin_amdgcn_exp2f(v * 2.885390081777927f);
    return 1.0f - 2.0f * __builtin_amdgcn_rcpf(e + 1.0f);
}

// launch_bounds(256, 2): 256-VGPR budget per wave. Round-1 run with (256,4)
// (128-VGPR cap) forced h[50]+acc[50] into AGPRs -> v_accvgpr copy per FMA,
// VGPR_Count=52, 59.5 TF effective vs 157 TF ceiling. The ~100-float live set
// across the layer boundary is structural; give it arch VGPRs.
__global__ __launch_bounds__(256, 2) void softmesh_mlp(
    const float* __restrict__ x, const float* __restrict__ y,
    const float* __restrict__ z,
    const float* __restrict__ W_in, const float* __restrict__ b_in,
    const float* __restrict__ W_mid, const float* __restrict__ b_mid,
    const float* __restrict__ W_out, const float* __restrict__ b_out,
    float* __restrict__ out, int n)
{
    int i = blockIdx.x * blockDim.x + threadIdx.x;
    if (i >= n) return;

    float in0 = x[i];
    float in1 = y[i];
    float in2 = z[i];

    float h[HID];
    float acc[HID];

    // input layer: [3] @ [3,50] + b -> tanh
#pragma unroll
    for (int j = 0; j < HID; ++j) {
        float a = b_in[j];
        a = fmaf(in0, W_in[0 * HID + j], a);
        a = fmaf(in1, W_in[1 * HID + j], a);
        a = fmaf(in2, W_in[2 * HID + j], a);
        h[j] = tanh_fast(a);
    }

    // 7 mid layers: [50] @ [50,50] + b -> tanh
    // Layer loop stays ROLLED: body ~2500 v_fmac; unrolling x7 blows I-cache.
#pragma unroll 1
    for (int L = 0; L < NMID; ++L) {
        const float* __restrict__ W = W_mid + L * HID * HID;
        const float* __restrict__ b = b_mid + L * HID;
#pragma unroll
        for (int j = 0; j < HID; ++j) acc[j] = b[j];
#pragma unroll
        for (int k = 0; k < HID; ++k) {
            float hk = h[k];
            // W row k contiguous + wave-uniform -> s_load; FMA src0 = SGPR
#pragma unroll
            for (int j = 0; j < HID; ++j) {
                acc[j] = fmaf(hk, W[k * HID + j], acc[j]);
            }
        }
#pragma unroll
        for (int j = 0; j < HID; ++j) h[j] = tanh_fast(acc[j]);
    }

    // output layer: [50] @ [50,3] + b
    float u0 = b_out[0];
    float u1 = b_out[1];
    float u2 = b_out[2];
#pragma unroll
    for (int k = 0; k < HID; ++k) {
        float hk = h[k];
        u0 = fmaf(hk, W_out[k * 3 + 0], u0);
        u1 = fmaf(hk, W_out[k * 3 + 1], u1);
        u2 = fmaf(hk, W_out[k * 3 + 2], u2);
    }

    // outputs: tuple (U[:,0], U[:,1], U[:,2]) concatenated flat
    out[i]         = u0;
    out[i + n]     = u1;
    out[i + 2 * n] = u2;
}

extern "C" void kernel_launch(void* const* d_in, const int* in_sizes, int n_in,
                              void* d_out, int out_size, void* d_ws, size_t ws_size,
                              hipStream_t stream) {
    const float* x     = (const float*)d_in[0];
    const float* y     = (const float*)d_in[1];
    const float* z     = (const float*)d_in[2];
    const float* W_in  = (const float*)d_in[3];
    const float* b_in  = (const float*)d_in[4];
    const float* W_mid = (const float*)d_in[5];
    const float* b_mid = (const float*)d_in[6];
    const float* W_out = (const float*)d_in[7];
    const float* b_out = (const float*)d_in[8];
    float* out = (float*)d_out;

    int n = in_sizes[0];
    int block = 256;
    int grid = (n + block - 1) / block;
    softmesh_mlp<<<grid, block, 0, stream>>>(x, y, z, W_in, b_in, W_mid, b_mid,
                                             W_out, b_out, out, n);
}